// Round 1
// 188.975 us; speedup vs baseline: 1.0093x; 1.0093x over previous
//
#include <hip/hip_runtime.h>
#include <stdint.h>

#define IN_FEATURES 65536
#define OUT_FEATURES 262144
#define NUM_CONN 128
#define BLOCK 1024
#define WAVES (BLOCK / 64)          // 16 waves
#define OUT_PER_WAVE 64
#define GRID (OUT_FEATURES / (WAVES * OUT_PER_WAVE))   // 256 blocks, 1/CU (128 KiB LDS)

typedef int v4i __attribute__((ext_vector_type(4)));   // native vector: nontemporal-load OK

__device__ __forceinline__ float bf16_widen(uint16_t h) {
    return __uint_as_float(((uint32_t)h) << 16);
}

// DPP row-rotate move (row = 16 lanes). ctrl: row_ror:N = 0x120 | N.
template <int CTRL>
__device__ __forceinline__ float dpp_mov(float v) {
    int x = __builtin_amdgcn_update_dpp(0, __float_as_int(v), CTRL, 0xF, 0xF, true);
    return __int_as_float(x);
}

__global__ __launch_bounds__(BLOCK, 1)
void deep_agg_kernel(const float* __restrict__ x,
                     const int* __restrict__ conn,
                     const int* __restrict__ ops,
                     float* __restrict__ out) {
    __shared__ uint16_t xs[IN_FEATURES];   // 128 KiB bf16 copy of x
    const int tid  = threadIdx.x;
    const int lane = tid & 63;
    const int wv   = tid >> 6;
    const int j    = lane & 15;    // position within 16-lane row group
    const int g    = lane >> 4;    // which of 4 rows this round
    const int o_base = (blockIdx.x * WAVES + wv) * OUT_PER_WAVE;
    const int oidx   = o_base + 4 * j + g;

    // Row for group g in round r: o_base + 4*r + g. Round stride = 4 rows = 128 int4.
    const v4i* base = (const v4i*)(conn + (size_t)(o_base + g) * NUM_CONN);

    // ---- Prologue overlap: issue rounds 0/1 conn loads + op load BEFORE staging.
    // Their ~900-cycle HBM latency hides under the x->LDS staging phase instead of
    // being exposed right after __syncthreads when round 0 consumes a0.
    v4i a0 = __builtin_nontemporal_load(&base[j]);
    v4i a1 = __builtin_nontemporal_load(&base[j + 16]);
    v4i b0 = __builtin_nontemporal_load(&base[128 + j]);
    v4i b1 = __builtin_nontemporal_load(&base[128 + j + 16]);
    const int op = __builtin_nontemporal_load(&ops[oidx]);

    // ---- Stage x -> LDS as bf16 (RN), coalesced. unroll 4 keeps reg footprint
    // small so the pre-issued conn loads stay resident without pressure.
    const float4* x4 = (const float4*)x;
    #pragma unroll 4
    for (int k = 0; k < IN_FEATURES / 4 / BLOCK; ++k) {   // 16 iters
        int i4 = tid + k * BLOCK;
        float4 v = x4[i4];
        uint32_t a = __float_as_uint(v.x), b = __float_as_uint(v.y);
        uint32_t c = __float_as_uint(v.z), d = __float_as_uint(v.w);
        a += 0x7fffu + ((a >> 16) & 1u);
        b += 0x7fffu + ((b >> 16) & 1u);
        c += 0x7fffu + ((c >> 16) & 1u);
        d += 0x7fffu + ((d >> 16) & 1u);
        uint2 p;
        p.x = (a >> 16) | (b & 0xffff0000u);
        p.y = (c >> 16) | (d & 0xffff0000u);
        ((uint2*)xs)[i4] = p;
    }
    __syncthreads();

    float res_mn = 0.f, res_mx = 0.f;
    #pragma unroll
    for (int r = 0; r < 16; ++r) {
        v4i c0, c1;
        if (r < 14) {   // prefetch round r+2 while rounds r (here) and r+1 (in regs) proceed
            c0 = __builtin_nontemporal_load(&base[(r + 2) * 128 + j]);
            c1 = __builtin_nontemporal_load(&base[(r + 2) * 128 + j + 16]);
        }

        float f0 = bf16_widen(xs[a0.x]), f1 = bf16_widen(xs[a0.y]);
        float f2 = bf16_widen(xs[a0.z]), f3 = bf16_widen(xs[a0.w]);
        float f4 = bf16_widen(xs[a1.x]), f5 = bf16_widen(xs[a1.y]);
        float f6 = bf16_widen(xs[a1.z]), f7 = bf16_widen(xs[a1.w]);

        // min3/max3-fusable shape: fmin(fmin(X,Y),Z) -> v_min3_f32 (4 ops vs 7)
        float mn = fminf(fminf(fminf(fminf(f0, f1), f2),
                               fminf(fminf(f3, f4), f5)),
                         fminf(f6, f7));
        float mx = fmaxf(fmaxf(fmaxf(fmaxf(f0, f1), f2),
                               fmaxf(fmaxf(f3, f4), f5)),
                         fmaxf(f6, f7));

        // 16-lane reduction, pure VALU (DPP row rotates; LDS pipe stays free)
        mn = fminf(mn, dpp_mov<0x121>(mn));  mx = fmaxf(mx, dpp_mov<0x121>(mx));
        mn = fminf(mn, dpp_mov<0x122>(mn));  mx = fmaxf(mx, dpp_mov<0x122>(mx));
        mn = fminf(mn, dpp_mov<0x124>(mn));  mx = fmaxf(mx, dpp_mov<0x124>(mx));
        mn = fminf(mn, dpp_mov<0x128>(mn));  mx = fmaxf(mx, dpp_mov<0x128>(mx));

        // lane j == r keeps round r's result for its group-row
        bool keep = (j == r);
        res_mn = keep ? mn : res_mn;
        res_mx = keep ? mx : res_mx;

        a0 = b0; a1 = b1; b0 = c0; b1 = c1;   // rotate pipeline
    }

    // lane l holds output o_base + 4*(l&15) + (l>>4): dense permuted 256 B region
    __builtin_nontemporal_store((op == 0) ? res_mn : res_mx, &out[oidx]);
}

extern "C" void kernel_launch(void* const* d_in, const int* in_sizes, int n_in,
                              void* d_out, int out_size, void* d_ws, size_t ws_size,
                              hipStream_t stream) {
    const float* x    = (const float*)d_in[0];
    const int*   conn = (const int*)d_in[1];
    const int*   ops  = (const int*)d_in[2];
    float*       out  = (float*)d_out;
    deep_agg_kernel<<<GRID, BLOCK, 0, stream>>>(x, conn, ops, out);
}

// Round 2
// 187.008 us; speedup vs baseline: 1.0199x; 1.0105x over previous
//
#include <hip/hip_runtime.h>
#include <stdint.h>

#define IN_FEATURES 65536
#define OUT_FEATURES 262144
#define NUM_CONN 128
#define BLOCK 1024
#define WAVES (BLOCK / 64)          // 16 waves
#define OUT_PER_WAVE 64
#define GRID (OUT_FEATURES / (WAVES * OUT_PER_WAVE))   // 256 blocks, 1/CU (128 KiB LDS)
#define PIPE 6                      // conn prefetch depth (rounds in flight)

typedef int v4i __attribute__((ext_vector_type(4)));   // native vector: nontemporal-load OK

__device__ __forceinline__ float bf16_widen(uint16_t h) {
    return __uint_as_float(((uint32_t)h) << 16);
}

// DPP row-rotate move (row = 16 lanes). ctrl: row_ror:N = 0x120 | N.
template <int CTRL>
__device__ __forceinline__ float dpp_mov(float v) {
    int x = __builtin_amdgcn_update_dpp(0, __float_as_int(v), CTRL, 0xF, 0xF, true);
    return __int_as_float(x);
}

__global__ __launch_bounds__(BLOCK, 1)
void deep_agg_kernel(const float* __restrict__ x,
                     const int* __restrict__ conn,
                     const int* __restrict__ ops,
                     float* __restrict__ out) {
    __shared__ uint16_t xs[IN_FEATURES];   // 128 KiB bf16 copy of x
    const int tid  = threadIdx.x;
    const int lane = tid & 63;
    const int wv   = tid >> 6;
    const int j    = lane & 15;    // position within 16-lane row group
    const int g    = lane >> 4;    // which of 4 rows this round
    const int o_base = (blockIdx.x * WAVES + wv) * OUT_PER_WAVE;
    const int oidx   = o_base + 4 * j + g;

    // Row for group g in round r: o_base + 4*r + g. Round stride = 4 rows = 128 int4.
    const v4i* base = (const v4i*)(conn + (size_t)(o_base + g) * NUM_CONN);

    // ---- Prologue overlap: issue PIPE rounds of conn loads + the op load BEFORE
    // staging. 6 rounds = 192 B/lane = 192 KiB/CU in flight ~= 7.8 us of per-CU HBM
    // supply -- enough to keep HBM busy through the entire x->LDS staging phase
    // instead of going idle after the first 2 rounds' worth of data lands.
    v4i p0[PIPE], p1[PIPE];
    #pragma unroll
    for (int i = 0; i < PIPE; ++i) {       // compile-time indices: stays in VGPRs
        p0[i] = __builtin_nontemporal_load(&base[i * 128 + j]);
        p1[i] = __builtin_nontemporal_load(&base[i * 128 + j + 16]);
    }
    const int op = __builtin_nontemporal_load(&ops[oidx]);

    // ---- Stage x -> LDS as bf16 (RN), coalesced. unroll 4 keeps reg footprint
    // small so the 48-VGPR conn pipeline stays resident without spills.
    const float4* x4 = (const float4*)x;
    #pragma unroll 4
    for (int k = 0; k < IN_FEATURES / 4 / BLOCK; ++k) {   // 16 iters
        int i4 = tid + k * BLOCK;
        float4 v = x4[i4];
        uint32_t a = __float_as_uint(v.x), b = __float_as_uint(v.y);
        uint32_t c = __float_as_uint(v.z), d = __float_as_uint(v.w);
        a += 0x7fffu + ((a >> 16) & 1u);
        b += 0x7fffu + ((b >> 16) & 1u);
        c += 0x7fffu + ((c >> 16) & 1u);
        d += 0x7fffu + ((d >> 16) & 1u);
        uint2 p;
        p.x = (a >> 16) | (b & 0xffff0000u);
        p.y = (c >> 16) | (d & 0xffff0000u);
        ((uint2*)xs)[i4] = p;
    }
    __syncthreads();

    float res_mn = 0.f, res_mx = 0.f;
    #pragma unroll
    for (int r = 0; r < 16; ++r) {
        const int slot = r % PIPE;         // constant under full unroll
        v4i a0 = p0[slot], a1 = p1[slot];
        if (r < 16 - PIPE) {               // prefetch round r+PIPE into freed slot
            p0[slot] = __builtin_nontemporal_load(&base[(r + PIPE) * 128 + j]);
            p1[slot] = __builtin_nontemporal_load(&base[(r + PIPE) * 128 + j + 16]);
        }

        float f0 = bf16_widen(xs[a0.x]), f1 = bf16_widen(xs[a0.y]);
        float f2 = bf16_widen(xs[a0.z]), f3 = bf16_widen(xs[a0.w]);
        float f4 = bf16_widen(xs[a1.x]), f5 = bf16_widen(xs[a1.y]);
        float f6 = bf16_widen(xs[a1.z]), f7 = bf16_widen(xs[a1.w]);

        // min3/max3-fusable shape: fmin(fmin(X,Y),Z) -> v_min3_f32 (4 ops vs 7)
        float mn = fminf(fminf(fminf(fminf(f0, f1), f2),
                               fminf(fminf(f3, f4), f5)),
                         fminf(f6, f7));
        float mx = fmaxf(fmaxf(fmaxf(fmaxf(f0, f1), f2),
                               fmaxf(fmaxf(f3, f4), f5)),
                         fmaxf(f6, f7));

        // 16-lane reduction, pure VALU (DPP row rotates; LDS pipe stays free)
        mn = fminf(mn, dpp_mov<0x121>(mn));  mx = fmaxf(mx, dpp_mov<0x121>(mx));
        mn = fminf(mn, dpp_mov<0x122>(mn));  mx = fmaxf(mx, dpp_mov<0x122>(mx));
        mn = fminf(mn, dpp_mov<0x124>(mn));  mx = fmaxf(mx, dpp_mov<0x124>(mx));
        mn = fminf(mn, dpp_mov<0x128>(mn));  mx = fmaxf(mx, dpp_mov<0x128>(mx));

        // lane j == r keeps round r's result for its group-row
        bool keep = (j == r);
        res_mn = keep ? mn : res_mn;
        res_mx = keep ? mx : res_mx;
    }

    // lane l holds output o_base + 4*(l&15) + (l>>4): dense permuted 256 B region
    __builtin_nontemporal_store((op == 0) ? res_mn : res_mx, &out[oidx]);
}

extern "C" void kernel_launch(void* const* d_in, const int* in_sizes, int n_in,
                              void* d_out, int out_size, void* d_ws, size_t ws_size,
                              hipStream_t stream) {
    const float* x    = (const float*)d_in[0];
    const int*   conn = (const int*)d_in[1];
    const int*   ops  = (const int*)d_in[2];
    float*       out  = (float*)d_out;
    deep_agg_kernel<<<GRID, BLOCK, 0, stream>>>(x, conn, ops, out);
}